// Round 8
// baseline (241.326 us; speedup 1.0000x reference)
//
#include <hip/hip_runtime.h>
#include <math.h>

#define HDIM 4096
#define THREADS 256
#define CHUNK 4          // HDIM / (THREADS * 4) float4 chunks per thread
#define EPSV 1e-6f

typedef float f4 __attribute__((ext_vector_type(4)));

__device__ __forceinline__ float waveSum(float v) {
    #pragma unroll
    for (int o = 32; o > 0; o >>= 1) v += __shfl_xor(v, o);
    return v;
}
__device__ __forceinline__ float waveMax(float v) {
    #pragma unroll
    for (int o = 32; o > 0; o >>= 1) v = fmaxf(v, __shfl_xor(v, o));
    return v;
}

// One block per row of 4096. R6 structure (NT stores + chunk rotation), plus
// per-wave/per-row rotation phase: decorrelates the instantaneous HBM
// channel/L2-set mix ACROSS the ~4K concurrent waves, not just within one
// thread's store sequence. Same addresses written, different time order.
__global__ __launch_bounds__(THREADS) void fused_add_rmsnorm_quant(
    const float* __restrict__ x1, const float* __restrict__ x2,
    const float* __restrict__ w,  const float* __restrict__ sm,
    float* __restrict__ out, const long long N, const long long R)
{
    __shared__ float redS[4];
    __shared__ float redW[4];
    __shared__ float redM[4];

    const int tid  = threadIdx.x;
    const int wave = tid >> 6;
    const int lane = tid & 63;
    const long long row  = blockIdx.x;
    const long long base = row * (long long)HDIM;
    const int rot  = (int)(row & 3) + wave;   // per-wave/per-row phase

    // ---- output layout: 10 outputs concatenated flat, all f32 ----
    float* out_q   = out;                 // yOut        [N]
    float* out_x   = out + N;             // xOut        [N]
    float* out_s1  = out + 2 * N;         // scale1Out   [R]
    float* out_y   = out + 2 * N + R;     // y1_flat     [N]
    float* out_xb  = out + 3 * N + R;     // xOut1       [N]
    float* out_q2  = out + 4 * N + R;     // yOut2       [N]
    float* out_x3  = out + 5 * N + 2 * R; // xOut3       [N]
    float* out_q3  = out + 6 * N + 2 * R; // yOut3       [N]
    float* out_s2  = out + 5 * N + R;     // scale1Out2  [R]
    float* out_s3  = out + 7 * N + 2 * R; // scale1Out3  [R]

    f4 xv[CHUNK];   // x1+x2 — the only state held across the barrier

    // ---- pass 1: load, add, row statistics ----
    float ss = 0.f, mW = 0.f, mSm = 0.f;
    #pragma unroll
    for (int c = 0; c < CHUNK; ++c) {
        const int col = c * (THREADS * 4) + tid * 4;
        const long long idx = base + col;
        const f4 a = __builtin_nontemporal_load(
            reinterpret_cast<const f4*>(x1 + idx));
        const f4 b = __builtin_nontemporal_load(
            reinterpret_cast<const f4*>(x2 + idx));
        const f4 wv  = *reinterpret_cast<const f4*>(w  + col);
        const f4 smv = *reinterpret_cast<const f4*>(sm + col);
        const f4 x = a + b;
        xv[c] = x;
        #pragma unroll
        for (int j = 0; j < 4; ++j) {
            const float t = x[j] * wv[j];     // y = t*inv
            ss += x[j] * x[j];
            mW  = fmaxf(mW,  fabsf(t));
            mSm = fmaxf(mSm, fabsf(t * smv[j]));
        }
    }

    // ---- x-streams, chunk-rotated per stream + wave/row phase ----
    #pragma unroll
    for (int c = 0; c < CHUNK; ++c) {
        const int c0 = (c + rot) & 3, c1 = (c + rot + 1) & 3, c2 = (c + rot + 2) & 3;
        __builtin_nontemporal_store(xv[c0], reinterpret_cast<f4*>(
            out_x  + base + c0 * (THREADS * 4) + tid * 4));
        __builtin_nontemporal_store(xv[c1], reinterpret_cast<f4*>(
            out_xb + base + c1 * (THREADS * 4) + tid * 4));
        __builtin_nontemporal_store(xv[c2], reinterpret_cast<f4*>(
            out_x3 + base + c2 * (THREADS * 4) + tid * 4));
    }

    ss  = waveSum(ss);
    mW  = waveMax(mW);
    mSm = waveMax(mSm);
    if (lane == 0) { redS[wave] = ss; redW[wave] = mW; redM[wave] = mSm; }
    __syncthreads();
    ss  = (redS[0] + redS[1]) + (redS[2] + redS[3]);
    mW  = fmaxf(fmaxf(redW[0], redW[1]), fmaxf(redW[2], redW[3]));
    mSm = fmaxf(fmaxf(redM[0], redM[1]), fmaxf(redM[2], redM[3]));

    const float inv    = 1.0f / sqrtf(ss * (1.0f / HDIM) + EPSV);
    const float scale1 = (inv * mSm) * (1.0f / 127.0f);
    const float scale3 = (inv * mW)  * (1.0f / 127.0f);
    const float rs1 = 1.0f / scale1;
    const float rs3 = 1.0f / scale3;

    // ---- pass 2: 4 streams, chunk-rotated per stream + wave/row phase ----
    #pragma unroll
    for (int c = 0; c < CHUNK; ++c) {
        const int cq  = (c + rot) & 3;
        const int cy  = (c + rot + 1) & 3;
        const int cq2 = (c + rot + 2) & 3;
        const int cq3 = (c + rot + 3) & 3;

        {   // q @ chunk cq
            const int col = cq * (THREADS * 4) + tid * 4;
            const f4 wv  = *reinterpret_cast<const f4*>(w  + col);
            const f4 smv = *reinterpret_cast<const f4*>(sm + col);
            f4 qf;
            #pragma unroll
            for (int j = 0; j < 4; ++j)
                qf[j] = rintf(xv[cq][j] * inv * wv[j] * smv[j] * rs1);
            __builtin_nontemporal_store(qf,
                reinterpret_cast<f4*>(out_q + base + col));
        }
        {   // y @ chunk cy
            const int col = cy * (THREADS * 4) + tid * 4;
            const f4 wv = *reinterpret_cast<const f4*>(w + col);
            f4 yq;
            #pragma unroll
            for (int j = 0; j < 4; ++j)
                yq[j] = xv[cy][j] * inv * wv[j];
            __builtin_nontemporal_store(yq,
                reinterpret_cast<f4*>(out_y + base + col));
        }
        {   // q2 @ chunk cq2
            const int col = cq2 * (THREADS * 4) + tid * 4;
            const f4 wv  = *reinterpret_cast<const f4*>(w  + col);
            const f4 smv = *reinterpret_cast<const f4*>(sm + col);
            f4 qf;
            #pragma unroll
            for (int j = 0; j < 4; ++j)
                qf[j] = rintf(xv[cq2][j] * inv * wv[j] * smv[j] * rs1);
            __builtin_nontemporal_store(qf,
                reinterpret_cast<f4*>(out_q2 + base + col));
        }
        {   // q3 @ chunk cq3
            const int col = cq3 * (THREADS * 4) + tid * 4;
            const f4 wv = *reinterpret_cast<const f4*>(w + col);
            f4 q3;
            #pragma unroll
            for (int j = 0; j < 4; ++j)
                q3[j] = rintf(xv[cq3][j] * inv * wv[j] * rs3);
            __builtin_nontemporal_store(q3,
                reinterpret_cast<f4*>(out_q3 + base + col));
        }
    }

    if (tid == 0) {
        out_s1[row] = scale1;
        out_s2[row] = scale1;
        out_s3[row] = scale3;
    }
}

extern "C" void kernel_launch(void* const* d_in, const int* in_sizes, int n_in,
                              void* d_out, int out_size, void* d_ws, size_t ws_size,
                              hipStream_t stream) {
    const float* x1 = (const float*)d_in[0];
    const float* x2 = (const float*)d_in[1];
    const float* w  = (const float*)d_in[2];
    const float* sm = (const float*)d_in[3];
    float* out = (float*)d_out;

    const long long N = (long long)in_sizes[0];   // 2*4096*4096
    const long long R = N / HDIM;                 // 8192 rows

    fused_add_rmsnorm_quant<<<dim3((unsigned)R), dim3(THREADS), 0, stream>>>(
        x1, x2, w, sm, out, N, R);
}

// Round 9
// 239.064 us; speedup vs baseline: 1.0095x; 1.0095x over previous
//
#include <hip/hip_runtime.h>
#include <math.h>

#define HDIM 4096
#define THREADS 256
#define CHUNK 4          // HDIM / (THREADS * 4) float4 chunks per thread
#define EPSV 1e-6f

typedef float f4 __attribute__((ext_vector_type(4)));

__device__ __forceinline__ float waveSum(float v) {
    #pragma unroll
    for (int o = 32; o > 0; o >>= 1) v += __shfl_xor(v, o);
    return v;
}
__device__ __forceinline__ float waveMax(float v) {
    #pragma unroll
    for (int o = 32; o > 0; o >>= 1) v = fmaxf(v, __shfl_xor(v, o));
    return v;
}

// x-only streams, chunk-rotated with COMPILE-TIME phase ROT (no runtime
// register-array indexing -> no scratch; rule #20).
template<int ROT>
__device__ __forceinline__ void storeX(const f4 (&xv)[CHUNK],
                                       float* __restrict__ out_x,
                                       float* __restrict__ out_xb,
                                       float* __restrict__ out_x3,
                                       long long base, int tid) {
    #pragma unroll
    for (int c = 0; c < CHUNK; ++c) {
        constexpr int S = THREADS * 4;
        const int c0 = (c + ROT) & 3, c1 = (c + ROT + 1) & 3, c2 = (c + ROT + 2) & 3;
        __builtin_nontemporal_store(xv[c0],
            reinterpret_cast<f4*>(out_x  + base + c0 * S + tid * 4));
        __builtin_nontemporal_store(xv[c1],
            reinterpret_cast<f4*>(out_xb + base + c1 * S + tid * 4));
        __builtin_nontemporal_store(xv[c2],
            reinterpret_cast<f4*>(out_x3 + base + c2 * S + tid * 4));
    }
}

// norm/quant streams, chunk-rotated with compile-time phase ROT.
template<int ROT>
__device__ __forceinline__ void storeQ(const f4 (&xv)[CHUNK],
                                       const float* __restrict__ w,
                                       const float* __restrict__ sm,
                                       float inv, float rs1, float rs3,
                                       float* __restrict__ out_q,
                                       float* __restrict__ out_y,
                                       float* __restrict__ out_q2,
                                       float* __restrict__ out_q3,
                                       long long base, int tid) {
    #pragma unroll
    for (int c = 0; c < CHUNK; ++c) {
        constexpr int S = THREADS * 4;
        const int cq  = (c + ROT) & 3;
        const int cy  = (c + ROT + 1) & 3;
        const int cq2 = (c + ROT + 2) & 3;
        const int cq3 = (c + ROT + 3) & 3;

        {   // q @ chunk cq
            const int col = cq * S + tid * 4;
            const f4 wv  = *reinterpret_cast<const f4*>(w  + col);
            const f4 smv = *reinterpret_cast<const f4*>(sm + col);
            f4 qf;
            #pragma unroll
            for (int j = 0; j < 4; ++j)
                qf[j] = rintf(xv[cq][j] * inv * wv[j] * smv[j] * rs1);
            __builtin_nontemporal_store(qf,
                reinterpret_cast<f4*>(out_q + base + col));
        }
        {   // y @ chunk cy
            const int col = cy * S + tid * 4;
            const f4 wv = *reinterpret_cast<const f4*>(w + col);
            f4 yq;
            #pragma unroll
            for (int j = 0; j < 4; ++j)
                yq[j] = xv[cy][j] * inv * wv[j];
            __builtin_nontemporal_store(yq,
                reinterpret_cast<f4*>(out_y + base + col));
        }
        {   // q2 @ chunk cq2
            const int col = cq2 * S + tid * 4;
            const f4 wv  = *reinterpret_cast<const f4*>(w  + col);
            const f4 smv = *reinterpret_cast<const f4*>(sm + col);
            f4 qf;
            #pragma unroll
            for (int j = 0; j < 4; ++j)
                qf[j] = rintf(xv[cq2][j] * inv * wv[j] * smv[j] * rs1);
            __builtin_nontemporal_store(qf,
                reinterpret_cast<f4*>(out_q2 + base + col));
        }
        {   // q3 @ chunk cq3
            const int col = cq3 * S + tid * 4;
            const f4 wv = *reinterpret_cast<const f4*>(w + col);
            f4 q3;
            #pragma unroll
            for (int j = 0; j < 4; ++j)
                q3[j] = rintf(xv[cq3][j] * inv * wv[j] * rs3);
            __builtin_nontemporal_store(q3,
                reinterpret_cast<f4*>(out_q3 + base + col));
        }
    }
}

// One block per row of 4096. R6 structure (NT stores + chunk rotation) with a
// CROSS-WAVE rotation phase applied via wave-uniform switch over 4
// compile-time template instantiations (R8 retry without the scratch spill).
__global__ __launch_bounds__(THREADS) void fused_add_rmsnorm_quant(
    const float* __restrict__ x1, const float* __restrict__ x2,
    const float* __restrict__ w,  const float* __restrict__ sm,
    float* __restrict__ out, const long long N, const long long R)
{
    __shared__ float redS[4];
    __shared__ float redW[4];
    __shared__ float redM[4];

    const int tid  = threadIdx.x;
    const int wave = tid >> 6;
    const int lane = tid & 63;
    const long long row  = blockIdx.x;
    const long long base = row * (long long)HDIM;
    const int rot  = ((int)row + wave) & 3;   // wave-uniform phase

    // ---- output layout: 10 outputs concatenated flat, all f32 ----
    float* out_q   = out;                 // yOut        [N]
    float* out_x   = out + N;             // xOut        [N]
    float* out_s1  = out + 2 * N;         // scale1Out   [R]
    float* out_y   = out + 2 * N + R;     // y1_flat     [N]
    float* out_xb  = out + 3 * N + R;     // xOut1       [N]
    float* out_q2  = out + 4 * N + R;     // yOut2       [N]
    float* out_s2  = out + 5 * N + R;     // scale1Out2  [R]
    float* out_x3  = out + 5 * N + 2 * R; // xOut3       [N]
    float* out_q3  = out + 6 * N + 2 * R; // yOut3       [N]
    float* out_s3  = out + 7 * N + 2 * R; // scale1Out3  [R]

    f4 xv[CHUNK];   // x1+x2 — the only state held across the barrier

    // ---- pass 1: load, add, row statistics ----
    float ss = 0.f, mW = 0.f, mSm = 0.f;
    #pragma unroll
    for (int c = 0; c < CHUNK; ++c) {
        const int col = c * (THREADS * 4) + tid * 4;
        const long long idx = base + col;
        const f4 a = __builtin_nontemporal_load(
            reinterpret_cast<const f4*>(x1 + idx));
        const f4 b = __builtin_nontemporal_load(
            reinterpret_cast<const f4*>(x2 + idx));
        const f4 wv  = *reinterpret_cast<const f4*>(w  + col);
        const f4 smv = *reinterpret_cast<const f4*>(sm + col);
        const f4 x = a + b;
        xv[c] = x;
        #pragma unroll
        for (int j = 0; j < 4; ++j) {
            const float t = x[j] * wv[j];     // y = t*inv
            ss += x[j] * x[j];
            mW  = fmaxf(mW,  fabsf(t));
            mSm = fmaxf(mSm, fabsf(t * smv[j]));
        }
    }

    // ---- x-streams (wave-uniform compile-time rotation) ----
    switch (rot) {
        case 0: storeX<0>(xv, out_x, out_xb, out_x3, base, tid); break;
        case 1: storeX<1>(xv, out_x, out_xb, out_x3, base, tid); break;
        case 2: storeX<2>(xv, out_x, out_xb, out_x3, base, tid); break;
        default: storeX<3>(xv, out_x, out_xb, out_x3, base, tid); break;
    }

    ss  = waveSum(ss);
    mW  = waveMax(mW);
    mSm = waveMax(mSm);
    if (lane == 0) { redS[wave] = ss; redW[wave] = mW; redM[wave] = mSm; }
    __syncthreads();
    ss  = (redS[0] + redS[1]) + (redS[2] + redS[3]);
    mW  = fmaxf(fmaxf(redW[0], redW[1]), fmaxf(redW[2], redW[3]));
    mSm = fmaxf(fmaxf(redM[0], redM[1]), fmaxf(redM[2], redM[3]));

    const float inv    = 1.0f / sqrtf(ss * (1.0f / HDIM) + EPSV);
    const float scale1 = (inv * mSm) * (1.0f / 127.0f);
    const float scale3 = (inv * mW)  * (1.0f / 127.0f);
    const float rs1 = 1.0f / scale1;
    const float rs3 = 1.0f / scale3;

    // ---- norm/quant streams (wave-uniform compile-time rotation) ----
    switch (rot) {
        case 0: storeQ<0>(xv, w, sm, inv, rs1, rs3, out_q, out_y, out_q2, out_q3, base, tid); break;
        case 1: storeQ<1>(xv, w, sm, inv, rs1, rs3, out_q, out_y, out_q2, out_q3, base, tid); break;
        case 2: storeQ<2>(xv, w, sm, inv, rs1, rs3, out_q, out_y, out_q2, out_q3, base, tid); break;
        default: storeQ<3>(xv, w, sm, inv, rs1, rs3, out_q, out_y, out_q2, out_q3, base, tid); break;
    }

    if (tid == 0) {
        out_s1[row] = scale1;
        out_s2[row] = scale1;
        out_s3[row] = scale3;
    }
}

extern "C" void kernel_launch(void* const* d_in, const int* in_sizes, int n_in,
                              void* d_out, int out_size, void* d_ws, size_t ws_size,
                              hipStream_t stream) {
    const float* x1 = (const float*)d_in[0];
    const float* x2 = (const float*)d_in[1];
    const float* w  = (const float*)d_in[2];
    const float* sm = (const float*)d_in[3];
    float* out = (float*)d_out;

    const long long N = (long long)in_sizes[0];   // 2*4096*4096
    const long long R = N / HDIM;                 // 8192 rows

    fused_add_rmsnorm_quant<<<dim3((unsigned)R), dim3(THREADS), 0, stream>>>(
        x1, x2, w, sm, out, N, R);
}

// Round 10
// 221.145 us; speedup vs baseline: 1.0913x; 1.0810x over previous
//
#include <hip/hip_runtime.h>
#include <math.h>

#define HDIM 4096
#define THREADS 256
#define CHUNK 4          // HDIM / (THREADS * 4) float4 chunks per thread
#define EPSV 1e-6f

typedef float f4 __attribute__((ext_vector_type(4)));

__device__ __forceinline__ float waveSum(float v) {
    #pragma unroll
    for (int o = 32; o > 0; o >>= 1) v += __shfl_xor(v, o);
    return v;
}
__device__ __forceinline__ float waveMax(float v) {
    #pragma unroll
    for (int o = 32; o > 0; o >>= 1) v = fmaxf(v, __shfl_xor(v, o));
    return v;
}

// One block per row of 4096. R6 base (NT loads+stores) with STREAM-OUTER
// store ordering: each thread writes all 4 chunks of one output stream
// back-to-back before touching the next stream. Temporally-adjacent stores
// stay within one stream (4KB strides) instead of jumping between streams
// whose bases alias in channel/bank bits (multiples of 2^29) -> avoids
// DRAM row-buffer thrash. Pure ordering A/B vs R6.
__global__ __launch_bounds__(THREADS) void fused_add_rmsnorm_quant(
    const float* __restrict__ x1, const float* __restrict__ x2,
    const float* __restrict__ w,  const float* __restrict__ sm,
    float* __restrict__ out, const long long N, const long long R)
{
    __shared__ float redS[4];
    __shared__ float redW[4];
    __shared__ float redM[4];

    const int tid  = threadIdx.x;
    const int wave = tid >> 6;
    const int lane = tid & 63;
    const long long row  = blockIdx.x;
    const long long base = row * (long long)HDIM;

    // ---- output layout: 10 outputs concatenated flat, all f32 ----
    float* out_q   = out;                 // yOut        [N]
    float* out_x   = out + N;             // xOut        [N]
    float* out_s1  = out + 2 * N;         // scale1Out   [R]
    float* out_y   = out + 2 * N + R;     // y1_flat     [N]
    float* out_xb  = out + 3 * N + R;     // xOut1       [N]
    float* out_q2  = out + 4 * N + R;     // yOut2       [N]
    float* out_s2  = out + 5 * N + R;     // scale1Out2  [R]
    float* out_x3  = out + 5 * N + 2 * R; // xOut3       [N]
    float* out_q3  = out + 6 * N + 2 * R; // yOut3       [N]
    float* out_s3  = out + 7 * N + 2 * R; // scale1Out3  [R]

    f4 xv[CHUNK];   // x1+x2 — the only state held across the barrier

    // ---- pass 1: load, add, row statistics ----
    float ss = 0.f, mW = 0.f, mSm = 0.f;
    #pragma unroll
    for (int c = 0; c < CHUNK; ++c) {
        const int col = c * (THREADS * 4) + tid * 4;
        const long long idx = base + col;
        const f4 a = __builtin_nontemporal_load(
            reinterpret_cast<const f4*>(x1 + idx));
        const f4 b = __builtin_nontemporal_load(
            reinterpret_cast<const f4*>(x2 + idx));
        const f4 wv  = *reinterpret_cast<const f4*>(w  + col);
        const f4 smv = *reinterpret_cast<const f4*>(sm + col);
        const f4 x = a + b;
        xv[c] = x;
        #pragma unroll
        for (int j = 0; j < 4; ++j) {
            const float t = x[j] * wv[j];     // y = t*inv
            ss += x[j] * x[j];
            mW  = fmaxf(mW,  fabsf(t));
            mSm = fmaxf(mSm, fabsf(t * smv[j]));
        }
    }

    // ---- x-streams, stream-outer: all chunks of one stream, then next ----
    #pragma unroll
    for (int c = 0; c < CHUNK; ++c)
        __builtin_nontemporal_store(xv[c], reinterpret_cast<f4*>(
            out_x  + base + c * (THREADS * 4) + tid * 4));
    #pragma unroll
    for (int c = 0; c < CHUNK; ++c)
        __builtin_nontemporal_store(xv[c], reinterpret_cast<f4*>(
            out_xb + base + c * (THREADS * 4) + tid * 4));
    #pragma unroll
    for (int c = 0; c < CHUNK; ++c)
        __builtin_nontemporal_store(xv[c], reinterpret_cast<f4*>(
            out_x3 + base + c * (THREADS * 4) + tid * 4));

    ss  = waveSum(ss);
    mW  = waveMax(mW);
    mSm = waveMax(mSm);
    if (lane == 0) { redS[wave] = ss; redW[wave] = mW; redM[wave] = mSm; }
    __syncthreads();
    ss  = (redS[0] + redS[1]) + (redS[2] + redS[3]);
    mW  = fmaxf(fmaxf(redW[0], redW[1]), fmaxf(redW[2], redW[3]));
    mSm = fmaxf(fmaxf(redM[0], redM[1]), fmaxf(redM[2], redM[3]));

    const float inv    = 1.0f / sqrtf(ss * (1.0f / HDIM) + EPSV);
    const float scale1 = (inv * mSm) * (1.0f / 127.0f);
    const float scale3 = (inv * mW)  * (1.0f / 127.0f);
    const float rs1 = 1.0f / scale1;
    const float rs3 = 1.0f / scale3;

    // ---- pass 2: stream-outer — q fully, then y, then q2, then q3 ----
    #pragma unroll
    for (int c = 0; c < CHUNK; ++c) {       // q
        const int col = c * (THREADS * 4) + tid * 4;
        const f4 wv  = *reinterpret_cast<const f4*>(w  + col);
        const f4 smv = *reinterpret_cast<const f4*>(sm + col);
        f4 qf;
        #pragma unroll
        for (int j = 0; j < 4; ++j)
            qf[j] = rintf(xv[c][j] * inv * wv[j] * smv[j] * rs1);
        __builtin_nontemporal_store(qf,
            reinterpret_cast<f4*>(out_q + base + col));
    }
    #pragma unroll
    for (int c = 0; c < CHUNK; ++c) {       // y
        const int col = c * (THREADS * 4) + tid * 4;
        const f4 wv = *reinterpret_cast<const f4*>(w + col);
        f4 yq;
        #pragma unroll
        for (int j = 0; j < 4; ++j)
            yq[j] = xv[c][j] * inv * wv[j];
        __builtin_nontemporal_store(yq,
            reinterpret_cast<f4*>(out_y + base + col));
    }
    #pragma unroll
    for (int c = 0; c < CHUNK; ++c) {       // q2
        const int col = c * (THREADS * 4) + tid * 4;
        const f4 wv  = *reinterpret_cast<const f4*>(w  + col);
        const f4 smv = *reinterpret_cast<const f4*>(sm + col);
        f4 qf;
        #pragma unroll
        for (int j = 0; j < 4; ++j)
            qf[j] = rintf(xv[c][j] * inv * wv[j] * smv[j] * rs1);
        __builtin_nontemporal_store(qf,
            reinterpret_cast<f4*>(out_q2 + base + col));
    }
    #pragma unroll
    for (int c = 0; c < CHUNK; ++c) {       // q3
        const int col = c * (THREADS * 4) + tid * 4;
        const f4 wv = *reinterpret_cast<const f4*>(w + col);
        f4 q3;
        #pragma unroll
        for (int j = 0; j < 4; ++j)
            q3[j] = rintf(xv[c][j] * inv * wv[j] * rs3);
        __builtin_nontemporal_store(q3,
            reinterpret_cast<f4*>(out_q3 + base + col));
    }

    if (tid == 0) {
        out_s1[row] = scale1;
        out_s2[row] = scale1;
        out_s3[row] = scale3;
    }
}

extern "C" void kernel_launch(void* const* d_in, const int* in_sizes, int n_in,
                              void* d_out, int out_size, void* d_ws, size_t ws_size,
                              hipStream_t stream) {
    const float* x1 = (const float*)d_in[0];
    const float* x2 = (const float*)d_in[1];
    const float* w  = (const float*)d_in[2];
    const float* sm = (const float*)d_in[3];
    float* out = (float*)d_out;

    const long long N = (long long)in_sizes[0];   // 2*4096*4096
    const long long R = N / HDIM;                 // 8192 rows

    fused_add_rmsnorm_quant<<<dim3((unsigned)R), dim3(THREADS), 0, stream>>>(
        x1, x2, w, sm, out, N, R);
}